// Round 1
// baseline (429.022 us; speedup 1.0000x reference)
//
#include <hip/hip_runtime.h>
#include <math.h>

#define NB 8
#define NC 1024
#define NH 64
#define NW 64
constexpr int PLANE = NH * NW;          // 4096
constexpr long long NTOT = (long long)NB * NC * PLANE;  // 33,554,432

// d_ws layout (floats):
// [0:512)     gsum_h   [b*64+h]  sum over c,w
// [512:1024)  gsum_v   [b*64+w]  sum over c,h
// [1024:1536) gsum_d   [b*64+l]  sum over c of x[b,c,l,l]
// [1536:2048) gsum_a   [b*64+l]  sum over c of x[b,c,l,63-l]
// [2048:2560) gate_h, [2560:3072) gate_v, [3072:3584) gate_d, [3584:4096) gate_a

__global__ __launch_bounds__(256) void zero_kernel(float* ws) {
    int i = blockIdx.x * 256 + threadIdx.x;
    if (i < 2048) ws[i] = 0.0f;
}

// grid = 1024 blocks: b = bid>>7, chunk of 8 c-planes = bid&127
__global__ __launch_bounds__(256) void reduce_kernel(const float* __restrict__ x,
                                                     float* __restrict__ gsum) {
    const int bid = blockIdx.x;
    const int b = bid >> 7;
    const int chunk = bid & 127;
    const int t = threadIdx.x;
    const int w0 = (t & 15) * 4;   // this thread's 4 fixed columns
    const int q  = t >> 4;         // row-within-pass (0..15)

    const float* base = x + ((size_t)b * NC + (size_t)chunk * 8) * PLANE;

    float colacc0 = 0.f, colacc1 = 0.f, colacc2 = 0.f, colacc3 = 0.f;
    float rowacc[4] = {0.f, 0.f, 0.f, 0.f};
    float diagacc = 0.f, antiacc = 0.f;

    for (int c = 0; c < 8; ++c) {
        const float4* pl = (const float4*)(base + (size_t)c * PLANE);
        #pragma unroll
        for (int p = 0; p < 4; ++p) {
            float4 v = pl[p * 256 + t];
            colacc0 += v.x; colacc1 += v.y; colacc2 += v.z; colacc3 += v.w;
            rowacc[p] += v.x + v.y + v.z + v.w;
            int h = p * 16 + q;
            // diag element (h,h): in [w0,w0+4) ?
            float dv = (h == w0)     ? v.x :
                       (h == w0 + 1) ? v.y :
                       (h == w0 + 2) ? v.z :
                       (h == w0 + 3) ? v.w : 0.f;
            diagacc += dv;
            int ac = 63 - h;  // anti-diag column for this row
            float av = (ac == w0)     ? v.x :
                       (ac == w0 + 1) ? v.y :
                       (ac == w0 + 2) ? v.z :
                       (ac == w0 + 3) ? v.w : 0.f;
            antiacc += av;
        }
    }

    __shared__ float rowpart[4][256];
    __shared__ float colpart[256][4];
    __shared__ float sdiag[64];
    __shared__ float santi[64];

    #pragma unroll
    for (int p = 0; p < 4; ++p) rowpart[p][t] = rowacc[p];
    colpart[t][0] = colacc0; colpart[t][1] = colacc1;
    colpart[t][2] = colacc2; colpart[t][3] = colacc3;

    // unique owner threads deposit diag/anti partials
    {
        int dj = (q - w0) & 15;           // h = w0+dj has h%16==q
        if (dj < 4) sdiag[w0 + dj] = diagacc;
        int ak = (q - (60 - w0)) & 15;    // h = 60-w0+ak has h%16==q
        if (ak < 4) santi[60 - w0 + ak] = antiacc;
    }
    __syncthreads();

    if (t < 64) {
        int r = t;
        float s = 0.f;
        #pragma unroll
        for (int k = 0; k < 16; ++k) s += rowpart[r >> 4][(r & 15) * 16 + k];
        atomicAdd(gsum + b * 64 + r, s);
    } else if (t < 128) {
        int w = t - 64;
        float s = 0.f;
        #pragma unroll
        for (int k = 0; k < 16; ++k) s += colpart[(w >> 2) + k * 16][w & 3];
        atomicAdd(gsum + 512 + b * 64 + w, s);
    } else if (t < 192) {
        int r = t - 128;
        atomicAdd(gsum + 1024 + b * 64 + r, sdiag[r]);
    } else {
        int r = t - 192;
        atomicAdd(gsum + 1536 + b * 64 + r, santi[r]);
    }
}

struct GateW {
    const float* w0;  // (1,1,5,5) flat 25
    const float* w1;  // (1,1,7,7) flat 49
    const float* ws;  // (2,2,1,1) flat 4
    const float* bs;  // (2,)
};

__device__ __forceinline__ float sigmoidf_(float v) {
    return 1.f / (1.f + expf(-v));
}

// grid = 8 blocks (one per b), 256 threads: wave g = gate index (0=h,1=v,2=d,3=a)
__global__ __launch_bounds__(256) void gate_kernel(const float* __restrict__ gsum,
                                                   GateW g0, GateW g1, GateW g2, GateW g3,
                                                   float* __restrict__ gates) {
    const int b = blockIdx.x;
    const int t = threadIdx.x;
    const int g = t >> 6;   // wave-uniform
    const int l = t & 63;

    GateW gw = (g == 0) ? g0 : (g == 1) ? g1 : (g == 2) ? g2 : g3;
    const float scale = (g < 2) ? (1.0f / 65536.0f) : (1.0f / 1024.0f);

    __shared__ float xm[4][64];
    __shared__ float u1s[4][64];

    xm[g][l] = gsum[g * 512 + b * 64 + l] * scale;
    __syncthreads();

    // 5-tap conv: h-gate uses kernel column 2 (w0[i*5+2]); others row 2 (w0[10+i])
    float u1v = 0.f;
    #pragma unroll
    for (int i = 0; i < 5; ++i) {
        float wv = gw.w0[(g == 0) ? (i * 5 + 2) : (10 + i)];
        int idx = l - 2 + i;
        if (idx >= 0 && idx < 64) u1v += xm[g][idx] * wv;
    }
    u1s[g][l] = u1v;
    __syncthreads();

    // 7-tap dil-3 conv: h-gate uses column 3 (w1[i*7+3]); others row 3 (w1[21+i])
    float u2v = 0.f;
    #pragma unroll
    for (int i = 0; i < 7; ++i) {
        float wv = gw.w1[(g == 0) ? (i * 7 + 3) : (21 + i)];
        int idx = l - 9 + 3 * i;
        if (idx >= 0 && idx < 64) u2v += u1s[g][idx] * wv;
    }

    float avg = 0.5f * (u1v + u2v);
    float mx  = fmaxf(u1v, u2v);
    float a0 = sigmoidf_(gw.ws[0] * avg + gw.ws[1] * mx + gw.bs[0]);
    float a1 = sigmoidf_(gw.ws[2] * avg + gw.ws[3] * mx + gw.bs[1]);
    float res = u1v * a0 + u2v * a1;
    gates[g * 512 + b * 64 + l] = sigmoidf_(res);
}

__global__ __launch_bounds__(256) void apply_kernel(const float* __restrict__ x,
                                                    const float* __restrict__ gates,
                                                    const float* __restrict__ fb_p,
                                                    float* __restrict__ out) {
    const float fb = fb_p[0];
    const size_t n4 = (size_t)NTOT / 4;        // 8,388,608 float4s
    const size_t stride = (size_t)gridDim.x * blockDim.x;
    const float4* x4 = (const float4*)x;
    float4* oh = (float4*)out;
    float4* ov = (float4*)(out + (size_t)NTOT);

    for (size_t i = (size_t)blockIdx.x * blockDim.x + threadIdx.x; i < n4; i += stride) {
        size_t e = i * 4;
        int w0 = (int)(e & 63);
        int h  = (int)((e >> 6) & 63);
        int b  = (int)(e >> 22);

        float4 v = x4[i];
        float ah = gates[b * 64 + h];
        float4 av = *(const float4*)(gates + 512 + b * 64 + w0);
        float gd = gates[1024 + b * 64 + h];
        float ga = gates[1536 + b * 64 + h];

        int hw = 63 - h;
        float sc0 = 1.f + fb * (((w0 + 0 == h) ? gd : 0.f) + ((w0 + 0 == hw) ? ga : 0.f));
        float sc1 = 1.f + fb * (((w0 + 1 == h) ? gd : 0.f) + ((w0 + 1 == hw) ? ga : 0.f));
        float sc2 = 1.f + fb * (((w0 + 2 == h) ? gd : 0.f) + ((w0 + 2 == hw) ? ga : 0.f));
        float sc3 = 1.f + fb * (((w0 + 3 == h) ? gd : 0.f) + ((w0 + 3 == hw) ? ga : 0.f));

        float4 o1, o2;
        o1.x = v.x * ah * sc0;  o1.y = v.y * ah * sc1;
        o1.z = v.z * ah * sc2;  o1.w = v.w * ah * sc3;
        o2.x = v.x * av.x * sc0; o2.y = v.y * av.y * sc1;
        o2.z = v.z * av.z * sc2; o2.w = v.w * av.w * sc3;

        oh[i] = o1;
        ov[i] = o2;
    }
}

extern "C" void kernel_launch(void* const* d_in, const int* in_sizes, int n_in,
                              void* d_out, int out_size, void* d_ws, size_t ws_size,
                              hipStream_t stream) {
    const float* x = (const float*)d_in[0];
    float* wsf = (float*)d_ws;

    GateW gh { (const float*)d_in[1],  (const float*)d_in[2],  (const float*)d_in[3],  (const float*)d_in[4]  };
    GateW gv { (const float*)d_in[5],  (const float*)d_in[6],  (const float*)d_in[7],  (const float*)d_in[8]  };
    GateW gd { (const float*)d_in[9],  (const float*)d_in[10], (const float*)d_in[11], (const float*)d_in[12] };
    GateW ga { (const float*)d_in[13], (const float*)d_in[14], (const float*)d_in[15], (const float*)d_in[16] };
    const float* fb = (const float*)d_in[17];

    zero_kernel<<<8, 256, 0, stream>>>(wsf);
    reduce_kernel<<<1024, 256, 0, stream>>>(x, wsf);
    gate_kernel<<<NB, 256, 0, stream>>>(wsf, gh, gv, gd, ga, wsf + 2048);
    apply_kernel<<<4096, 256, 0, stream>>>(x, wsf + 2048, fb, (float*)d_out);
}

// Round 2
// 409.792 us; speedup vs baseline: 1.0469x; 1.0469x over previous
//
#include <hip/hip_runtime.h>
#include <math.h>

#define NB 8
#define NC 1024
#define NH 64
#define NW 64
constexpr int PLANE = NH * NW;          // 4096
constexpr long long NTOT = (long long)NB * NC * PLANE;  // 33,554,432

constexpr int RBLK = 512;               // reduce blocks
constexpr int CHUNKS = RBLK / NB;       // 64 chunks per batch
constexpr int CPLANES = NC / CHUNKS;    // 16 planes per block

typedef float f4 __attribute__((ext_vector_type(4)));

// d_ws layout (floats):
// [0 : RBLK*256)            per-block partials: blk*256 + {0:64 row, 64:128 col, 128:192 diag, 192:256 anti}
// [RBLK*256 : RBLK*256+2048) gates: g*512 + b*64 + l   (g: 0=h,1=v,2=d,3=a)

// grid = RBLK blocks: b = bid/CHUNKS, chunk = bid%CHUNKS (CPLANES c-planes each)
__global__ __launch_bounds__(256) void reduce_kernel(const float* __restrict__ x,
                                                     float* __restrict__ part) {
    const int bid = blockIdx.x;
    const int b = bid >> 6;          // CHUNKS = 64
    const int chunk = bid & 63;
    const int t = threadIdx.x;
    const int w0 = (t & 15) * 4;     // this thread's 4 fixed columns
    const int q  = t >> 4;           // row-within-pass (0..15)

    const f4* base = (const f4*)(x + ((size_t)b * NC + (size_t)chunk * CPLANES) * PLANE);

    float colacc0 = 0.f, colacc1 = 0.f, colacc2 = 0.f, colacc3 = 0.f;
    float rowacc[4] = {0.f, 0.f, 0.f, 0.f};
    float diagacc = 0.f, antiacc = 0.f;

    for (int c = 0; c < CPLANES; ++c) {
        const f4* pl = base + (size_t)c * (PLANE / 4);
        #pragma unroll
        for (int p = 0; p < 4; ++p) {
            f4 v = pl[p * 256 + t];
            colacc0 += v.x; colacc1 += v.y; colacc2 += v.z; colacc3 += v.w;
            rowacc[p] += (v.x + v.y) + (v.z + v.w);
            int h = p * 16 + q;
            float dv = (h == w0)     ? v.x :
                       (h == w0 + 1) ? v.y :
                       (h == w0 + 2) ? v.z :
                       (h == w0 + 3) ? v.w : 0.f;
            diagacc += dv;
            int ac = 63 - h;  // anti-diag column for this row
            float av = (ac == w0)     ? v.x :
                       (ac == w0 + 1) ? v.y :
                       (ac == w0 + 2) ? v.z :
                       (ac == w0 + 3) ? v.w : 0.f;
            antiacc += av;
        }
    }

    __shared__ float rowpart[4][256];
    __shared__ float colpart[256][4];
    __shared__ float sdiag[64];
    __shared__ float santi[64];

    #pragma unroll
    for (int p = 0; p < 4; ++p) rowpart[p][t] = rowacc[p];
    colpart[t][0] = colacc0; colpart[t][1] = colacc1;
    colpart[t][2] = colacc2; colpart[t][3] = colacc3;

    // unique owner threads deposit diag/anti partials
    {
        int dj = (q - w0) & 15;           // h = w0+dj has h%16==q
        if (dj < 4) sdiag[w0 + dj] = diagacc;
        int ak = (q - (60 - w0)) & 15;    // h = 60-w0+ak has h%16==q
        if (ak < 4) santi[60 - w0 + ak] = antiacc;
    }
    __syncthreads();

    float* outp = part + (size_t)bid * 256;
    if (t < 64) {
        int r = t;
        float s = 0.f;
        #pragma unroll
        for (int k = 0; k < 16; ++k) s += rowpart[r >> 4][(r & 15) * 16 + k];
        outp[r] = s;
    } else if (t < 128) {
        int w = t - 64;
        float s = 0.f;
        #pragma unroll
        for (int k = 0; k < 16; ++k) s += colpart[(w >> 2) + k * 16][w & 3];
        outp[64 + w] = s;
    } else if (t < 192) {
        int r = t - 128;
        outp[128 + r] = sdiag[r];
    } else {
        int r = t - 192;
        outp[192 + r] = santi[r];
    }
}

struct GateW {
    const float* w0;  // (1,1,5,5) flat 25
    const float* w1;  // (1,1,7,7) flat 49
    const float* ws;  // (2,2,1,1) flat 4
    const float* bs;  // (2,)
};

__device__ __forceinline__ float sigmoidf_(float v) {
    return 1.f / (1.f + expf(-v));
}

// grid = 8 blocks (one per b), 256 threads: wave g = gate index (0=h,1=v,2=d,3=a)
__global__ __launch_bounds__(256) void gate_kernel(const float* __restrict__ part,
                                                   GateW g0, GateW g1, GateW g2, GateW g3,
                                                   float* __restrict__ gates) {
    const int b = blockIdx.x;
    const int t = threadIdx.x;
    const int g = t >> 6;   // wave-uniform
    const int l = t & 63;

    GateW gw = (g == 0) ? g0 : (g == 1) ? g1 : (g == 2) ? g2 : g3;
    const float scale = (g < 2) ? (1.0f / 65536.0f) : (1.0f / 1024.0f);

    __shared__ float xm[4][64];
    __shared__ float u1s[4][64];

    // sum the CHUNKS per-block partials for this (b, g, l)
    {
        const float* pp = part + (size_t)b * CHUNKS * 256 + g * 64 + l;
        float s = 0.f;
        #pragma unroll 8
        for (int k = 0; k < CHUNKS; ++k) s += pp[(size_t)k * 256];
        xm[g][l] = s * scale;
    }
    __syncthreads();

    // 5-tap conv: h-gate uses kernel column 2 (w0[i*5+2]); others row 2 (w0[10+i])
    float u1v = 0.f;
    #pragma unroll
    for (int i = 0; i < 5; ++i) {
        float wv = gw.w0[(g == 0) ? (i * 5 + 2) : (10 + i)];
        int idx = l - 2 + i;
        if (idx >= 0 && idx < 64) u1v += xm[g][idx] * wv;
    }
    u1s[g][l] = u1v;
    __syncthreads();

    // 7-tap dil-3 conv: h-gate uses column 3 (w1[i*7+3]); others row 3 (w1[21+i])
    float u2v = 0.f;
    #pragma unroll
    for (int i = 0; i < 7; ++i) {
        float wv = gw.w1[(g == 0) ? (i * 7 + 3) : (21 + i)];
        int idx = l - 9 + 3 * i;
        if (idx >= 0 && idx < 64) u2v += u1s[g][idx] * wv;
    }

    float avg = 0.5f * (u1v + u2v);
    float mx  = fmaxf(u1v, u2v);
    float a0 = sigmoidf_(gw.ws[0] * avg + gw.ws[1] * mx + gw.bs[0]);
    float a1 = sigmoidf_(gw.ws[2] * avg + gw.ws[3] * mx + gw.bs[1]);
    float res = u1v * a0 + u2v * a1;
    gates[g * 512 + b * 64 + l] = sigmoidf_(res);
}

__global__ __launch_bounds__(256) void apply_kernel(const float* __restrict__ x,
                                                    const float* __restrict__ gates,
                                                    const float* __restrict__ fb_p,
                                                    float* __restrict__ out) {
    const float fb = fb_p[0];
    const unsigned n4 = (unsigned)(NTOT / 4);        // 8,388,608 float4s
    const unsigned stride = gridDim.x * blockDim.x;
    const f4* x4 = (const f4*)x;
    f4* oh = (f4*)out;
    f4* ov = (f4*)(out + (size_t)NTOT);

    for (unsigned i = blockIdx.x * blockDim.x + threadIdx.x; i < n4; i += stride) {
        unsigned e = i * 4u;
        int w0 = (int)(e & 63);
        int h  = (int)((e >> 6) & 63);
        int b  = (int)(e >> 22);

        f4 v = x4[i];
        float ah = gates[b * 64 + h];
        f4 av = *(const f4*)(gates + 512 + b * 64 + w0);
        float gd = gates[1024 + b * 64 + h];
        float ga = gates[1536 + b * 64 + h];

        int hw = 63 - h;
        float sc0 = 1.f + fb * (((w0 + 0 == h) ? gd : 0.f) + ((w0 + 0 == hw) ? ga : 0.f));
        float sc1 = 1.f + fb * (((w0 + 1 == h) ? gd : 0.f) + ((w0 + 1 == hw) ? ga : 0.f));
        float sc2 = 1.f + fb * (((w0 + 2 == h) ? gd : 0.f) + ((w0 + 2 == hw) ? ga : 0.f));
        float sc3 = 1.f + fb * (((w0 + 3 == h) ? gd : 0.f) + ((w0 + 3 == hw) ? ga : 0.f));

        f4 o1, o2;
        o1.x = v.x * ah * sc0;  o1.y = v.y * ah * sc1;
        o1.z = v.z * ah * sc2;  o1.w = v.w * ah * sc3;
        o2.x = v.x * av.x * sc0; o2.y = v.y * av.y * sc1;
        o2.z = v.z * av.z * sc2; o2.w = v.w * av.w * sc3;

        // nontemporal: keep x resident in L3 (don't let 256 MB of output
        // writes evict the 128 MB input we just cached during reduce)
        __builtin_nontemporal_store(o1, &oh[i]);
        __builtin_nontemporal_store(o2, &ov[i]);
    }
}

extern "C" void kernel_launch(void* const* d_in, const int* in_sizes, int n_in,
                              void* d_out, int out_size, void* d_ws, size_t ws_size,
                              hipStream_t stream) {
    const float* x = (const float*)d_in[0];
    float* wsf = (float*)d_ws;
    float* part = wsf;
    float* gates = wsf + (size_t)RBLK * 256;

    GateW gh { (const float*)d_in[1],  (const float*)d_in[2],  (const float*)d_in[3],  (const float*)d_in[4]  };
    GateW gv { (const float*)d_in[5],  (const float*)d_in[6],  (const float*)d_in[7],  (const float*)d_in[8]  };
    GateW gd { (const float*)d_in[9],  (const float*)d_in[10], (const float*)d_in[11], (const float*)d_in[12] };
    GateW ga { (const float*)d_in[13], (const float*)d_in[14], (const float*)d_in[15], (const float*)d_in[16] };
    const float* fb = (const float*)d_in[17];

    reduce_kernel<<<RBLK, 256, 0, stream>>>(x, part);
    gate_kernel<<<NB, 256, 0, stream>>>(part, gh, gv, gd, ga, gates);
    apply_kernel<<<4096, 256, 0, stream>>>(x, gates, fb, (float*)d_out);
}